// Round 8
// baseline (325.176 us; speedup 1.0000x reference)
//
#include <hip/hip_runtime.h>

typedef unsigned long long u64;
typedef unsigned int u32;
typedef unsigned short ushort_t;

#define NA 10000
#define NE 320000
#define KN 10
#define GRID 50
#define NCELL (GRID * GRID)      // 2500 cells of width 2.0 over [0,100)^2
#define GATB 157                 // ceil(NA/64)

typedef __attribute__((ext_vector_type(8))) short short8v;
typedef __attribute__((ext_vector_type(4))) float f32x4;

// ---------------- bf16 helpers (RNE) ----------------
__device__ __forceinline__ u32 f2bf(float f) {
  union { float f; u32 u; } v; v.f = f;
  return (v.u + 0x7fffu + ((v.u >> 16) & 1u)) >> 16;
}
__device__ __forceinline__ float bf2f(u32 b) {
  union { u32 u; float f; } v; v.u = b << 16;
  return v.f;
}

// ---------------- top-10 (d2,idx) maintenance ----------------
__device__ __forceinline__ void insert10(u64* top, u64 key) {
#pragma unroll
  for (int t = 9; t > 0; --t) {
    u64 prev = top[t - 1];
    u64 cur = top[t];
    top[t] = (key < prev) ? prev : ((key < cur) ? key : cur);
  }
  top[0] = (key < top[0]) ? key : top[0];
}

__device__ __forceinline__ int cell_of(float2 p) {
  int cx = (int)(p.x * 0.5f);            // exact: *0.5 is a pow2 multiply
  int cy = (int)(p.y * 0.5f);
  cx = min(max(cx, 0), GRID - 1);
  cy = min(max(cy, 0), GRID - 1);
  return cy * GRID + cx;
}

// ---------------- fused: zero counters + W repack (independent ranges) ----------------
__global__ __launch_bounds__(256) void k_zero_packw(int* __restrict__ deg, int* __restrict__ cur,
                                                    int* __restrict__ chist, int* __restrict__ ccur,
                                                    const float* __restrict__ gfW,
                                                    ushort_t* __restrict__ Wh, ushort_t* __restrict__ Wlo) {
  int i = blockIdx.x * 256 + threadIdx.x;
  if (i < NA) deg[i] = 0;
  else if (i < 2 * NA) cur[i - NA] = 0;
  else if (i < 2 * NA + 2 * NCELL) chist[i - 2 * NA] = 0;
  else if (i < 2 * NA + 4 * NCELL) ccur[i - 2 * NA - 2 * NCELL] = 0;
  if (i < 131072) {   // W repack: f32 [l][t][k][n] -> bf16 hi/lo B-frag layout
    int l = i >> 16;
    int rem = i & 65535;
    int t = rem >> 14;
    int k = (rem >> 7) & 127;
    int n = rem & 127;
    float v = gfW[(size_t)i];
    int kt = k >> 5;
    int hi = (k >> 3) & 3;
    int j = k & 7;
    int ct = n >> 4;
    int lane = hi * 16 + (n & 15);
    size_t dst = (((((size_t)(l * 4 + t) * 4 + kt) * 8 + ct) * 64 + lane) * 8 + j);
    u32 h = f2bf(v);
    float r = v - bf2f(h);
    Wh[dst] = (ushort_t)h;
    Wlo[dst] = (ushort_t)f2bf(r);
  }
}

// ---------------- fused: edge-degree hist + cell hist + self MLP ----------------
__global__ __launch_bounds__(256) void k_hist_self(const int* __restrict__ edst,
                                                   const float2* __restrict__ apos,
                                                   const float2* __restrict__ tpos,
                                                   int* __restrict__ deg, int* __restrict__ chist,
                                                   const float* __restrict__ own_obs,
                                                   const float* __restrict__ W_self, const float* __restrict__ b_self,
                                                   float* __restrict__ x) {
  __shared__ float sW[512], sb[64];
  int t = threadIdx.x;
  for (int i = t; i < 512; i += 256) sW[i] = W_self[i];
  if (t < 64) sb[t] = b_self[t];
  __syncthreads();
  int i = blockIdx.x * 256 + t;
  if (i < NE) {
    atomicAdd(&deg[edst[i]], 1);
  } else if (i < NE + 2 * NA) {
    int ii = i - NE;
    int graph = (ii >= NA) ? 1 : 0;
    int idx = ii - graph * NA;
    float2 p = graph ? tpos[idx] : apos[idx];
    atomicAdd(&chist[graph * NCELL + cell_of(p)], 1);
  } else if (i < NE + 2 * NA + 8 * NA) {
    int gid = i - NE - 2 * NA;
    int q = gid >> 3;
    int c8 = (gid & 7) * 8;
    const float4* op = (const float4*)(own_obs + (size_t)q * 8);
    float4 o0 = op[0], o1 = op[1];
    float obs[8] = {o0.x, o0.y, o0.z, o0.w, o1.x, o1.y, o1.z, o1.w};
    float out[8];
#pragma unroll
    for (int jj = 0; jj < 8; ++jj) {
      int c = c8 + jj;
      float s = sb[c];
#pragma unroll
      for (int k = 0; k < 8; ++k) s += obs[k] * sW[k * 64 + c];
      out[jj] = s;
    }
    float* xrow = x + (size_t)q * 128 + c8;
    *(float4*)(xrow) = make_float4(out[0], out[1], out[2], out[3]);
    *(float4*)(xrow + 4) = make_float4(out[4], out[5], out[6], out[7]);
  }
}

// ---------------- fused scans: block 0 = edge CSR, block 1 = cell CSR ----------------
__global__ __launch_bounds__(1024) void k_scan_all(const int* __restrict__ deg, int* __restrict__ rp,
                                                   const int* __restrict__ chist, int* __restrict__ crp) {
  __shared__ int part[1024];
  int t = threadIdx.x;
  const int* in;
  int* out;
  int per, tot;
  if (blockIdx.x == 0) { in = deg; out = rp; per = 10; tot = NA; }
  else { in = chist; out = crp; per = 5; tot = 2 * NCELL; }
  int beg = min(t * per, tot), end = min(beg + per, tot);
  int s = 0;
  for (int i = beg; i < end; ++i) s += in[i];
  part[t] = s;
  __syncthreads();
  for (int o = 1; o < 1024; o <<= 1) {
    int v = part[t];
    int u = (t >= o) ? part[t - o] : 0;
    __syncthreads();
    part[t] = v + u;
    __syncthreads();
  }
  int base = (t > 0) ? part[t - 1] : 0;
  for (int i = beg; i < end; ++i) { out[i] = base; base += in[i]; }
  if (t == 1023) out[tot] = part[1023];
}

// ---------------- fused scatters: edges into CSR, points into cells ----------------
__global__ __launch_bounds__(256) void k_scatter_all(const int* __restrict__ esrc, const int* __restrict__ edst,
                                                     const int* __restrict__ rp, int* __restrict__ cur,
                                                     int* __restrict__ col,
                                                     const float2* __restrict__ apos, const float2* __restrict__ tpos,
                                                     const int* __restrict__ crp, int* __restrict__ ccur,
                                                     float2* __restrict__ ps, int* __restrict__ pid) {
  int i = blockIdx.x * 256 + threadIdx.x;
  if (i < NE) {
    int d = edst[i];
    int p = atomicAdd(&cur[d], 1);
    col[rp[d] + p] = esrc[i];
  } else if (i < NE + 2 * NA) {
    int ii = i - NE;
    int graph = (ii >= NA) ? 1 : 0;
    int idx = ii - graph * NA;
    float2 p = graph ? tpos[idx] : apos[idx];
    int gc = graph * NCELL + cell_of(p);
    int o = crp[gc] + atomicAdd(&ccur[gc], 1);
    ps[o] = p;
    pid[o] = idx;
  }
}

// ---------------- binned neighbor search: exact top-10 within radius ----------------
__global__ __launch_bounds__(256) void k_nbr2(const float2* __restrict__ apos,
                                              const int* __restrict__ rp,
                                              const float2* __restrict__ ps, const int* __restrict__ pid,
                                              int* __restrict__ a_idx, int* __restrict__ a_cnt,
                                              int* __restrict__ t_idx, int* __restrict__ t_cnt) {
  int tid = blockIdx.x * 256 + threadIdx.x;
  if (tid >= 2 * NA) return;
  int graph = (tid >= NA) ? 1 : 0;
  int q = tid - graph * NA;
  float2 qp = apos[q];
  int cx = min(max((int)(qp.x * 0.5f), 0), GRID - 1);
  int cy = min(max((int)(qp.y * 0.5f), 0), GRID - 1);

  u64 top[10];
#pragma unroll
  for (int t = 0; t < 10; ++t) top[t] = ~0ull;

  int x0 = max(cx - 1, 0), x1 = min(cx + 1, GRID - 1);
  int y0 = max(cy - 1, 0), y1 = min(cy + 1, GRID - 1);
  for (int yy = y0; yy <= y1; ++yy) {
    int cb = graph * NCELL + yy * GRID + x0;
    int ce = graph * NCELL + yy * GRID + x1;
    int b = rp[cb], e = rp[ce + 1];   // contiguous cells -> contiguous points
    for (int j = b; j < e; ++j) {
      float2 kp = ps[j];
      float dx = qp.x - kp.x;
      float dy = qp.y - kp.y;
      float d2 = __fadd_rn(__fmul_rn(dx, dx), __fmul_rn(dy, dy));
      int g = pid[j];
      if (d2 <= 4.0f && !(graph == 0 && g == q)) {
        u64 key = ((u64)__float_as_uint(d2) << 32) | (u32)g;
        if (key < top[9]) insert10(top, key);
      }
    }
  }
  int cnt = 0;
#pragma unroll
  for (int t = 0; t < 10; ++t) cnt += (top[t] != ~0ull) ? 1 : 0;
  int* oi = graph ? t_idx : a_idx;
#pragma unroll
  for (int t = 0; t < 10; ++t) oi[(size_t)q * 10 + t] = (int)(u32)(top[t] & 0xffffffffu);
  if (graph) t_cnt[q] = cnt; else a_cnt[q] = cnt;
}

// ---------------- both GATs in one launch (blocks [0,157)=agent, [157,314)=target) ----------------
__global__ __launch_bounds__(64) void k_gat2(const float2* __restrict__ apos, const float2* __restrict__ tpos,
                                             const int* __restrict__ a_idx, const int* __restrict__ a_cnt,
                                             const int* __restrict__ t_idx, const int* __restrict__ t_cnt,
                                             const float* __restrict__ agWl, const float* __restrict__ agWr,
                                             const float* __restrict__ agatt, const float* __restrict__ agb,
                                             const float* __restrict__ tgWl, const float* __restrict__ tgWr,
                                             const float* __restrict__ tgatt, const float* __restrict__ tgb,
                                             float* __restrict__ x) {
  int graph = (blockIdx.x >= GATB) ? 1 : 0;
  int b0 = blockIdx.x - graph * GATB;
  const float2* srcpos = graph ? tpos : apos;
  const int* idx_all = graph ? t_idx : a_idx;
  const int* cnt_all = graph ? t_cnt : a_cnt;
  const float* Wl = graph ? tgWl : agWl;
  const float* Wr = graph ? tgWr : agWr;
  const float* att = graph ? tgatt : agatt;
  const float* bbp = graph ? tgb : agb;
  int outoff = graph ? 96 : 64;

  __shared__ float sWl[64], sWr[64], satt[32], sbb[32];
  int t = threadIdx.x;
  sWl[t] = Wl[t];
  sWr[t] = Wr[t];
  if (t < 32) { satt[t] = att[t]; sbb[t] = bbp[t]; }
  __syncthreads();
  int q = b0 * 64 + t;
  if (q >= NA) return;
  float2 qp = apos[q];
  float xr[32];
#pragma unroll
  for (int c = 0; c < 32; ++c) xr[c] = qp.x * sWr[c] + qp.y * sWr[32 + c];
  const int* il = idx_all + (size_t)q * 10;
  int cnt = cnt_all[q];
  int idx[10];
#pragma unroll
  for (int k = 0; k < 10; ++k) idx[k] = (k < cnt) ? il[k] : 0;
  float pv[10];
  float m = -1e30f;
#pragma unroll
  for (int k = 0; k < 10; ++k) {
    float2 p = srcpos[idx[k]];
    float s = 0.f;
#pragma unroll
    for (int c = 0; c < 32; ++c) {
      float xl = p.x * sWl[c] + p.y * sWl[32 + c];
      float g = xl + xr[c];
      g = (g >= 0.f) ? g : 0.2f * g;
      s += satt[c] * g;
    }
    pv[k] = s;
    m = (k < cnt) ? fmaxf(m, s) : m;
  }
  float sum = 0.f;
#pragma unroll
  for (int k = 0; k < 10; ++k) {
    float e = (k < cnt) ? expf(pv[k] - m) : 0.f;
    pv[k] = e;
    sum += e;
  }
  float inv = 1.f / (sum + 1e-16f);
  float out[32];
#pragma unroll
  for (int c = 0; c < 32; ++c) out[c] = sbb[c];
#pragma unroll
  for (int k = 0; k < 10; ++k) {
    float a = pv[k] * inv;
    float2 p = srcpos[idx[k]];   // re-gather: tables are L1/L2-hot
#pragma unroll
    for (int c = 0; c < 32; ++c) {
      float xl = p.x * sWl[c] + p.y * sWl[32 + c];
      out[c] += a * xl;
    }
  }
  float* xrow = x + (size_t)q * 128 + outoff;
#pragma unroll
  for (int c4 = 0; c4 < 8; ++c4)
    *(float4*)(xrow + c4 * 4) = make_float4(out[c4 * 4], out[c4 * 4 + 1], out[c4 * 4 + 2], out[c4 * 4 + 3]);
}

// ---------------- adjacency shift, XCD-partitioned channel halves ----------------
// half = (bid&7)>>2: XCDs 0-3 gather channels 0-63, XCDs 4-7 channels 64-127.
// nt output store: the written half lands in the WRONG XCD's L2 for the next shift
// anyway (readers are spread over 4 XCDs), so bypass L2 and keep the operand replica.
__global__ __launch_bounds__(256) void k_shift3(const float* __restrict__ xin, float* __restrict__ xout,
                                                const int* __restrict__ rp, const int* __restrict__ col) {
  int bid = blockIdx.x;                       // grid 1256
  int half = (bid & 7) >> 2;
  int slot = (bid >> 3) * 4 + (bid & 3);      // 0..627
  if (slot >= 625) return;
  int wid = threadIdx.x >> 6;
  int lane = threadIdx.x & 63;
  int q = lane >> 4;                          // quarter-wave owns one row
  int li = lane & 15;                         // 16 lanes x f32x4 = 64 channels
  int row = slot * 16 + wid * 4 + q;
  int beg = rp[row], end = rp[row + 1];
  const f32x4* x4 = (const f32x4*)xin;
  int base = half * 16 + li;
  f32x4 acc = {0.f, 0.f, 0.f, 0.f};
  int j = beg;
  for (; j + 1 < end; j += 2) {
    int s0 = col[j], s1 = col[j + 1];         // uniform in quarter -> broadcast
    f32x4 v0 = x4[(size_t)s0 * 32 + base];
    f32x4 v1 = x4[(size_t)s1 * 32 + base];
    acc += v0;
    acc += v1;
  }
  if (j < end) acc += x4[(size_t)col[j] * 32 + base];
  __builtin_nontemporal_store(acc, &((f32x4*)xout)[(size_t)row * 32 + base]);
}

// ---------------- MFMA 4-tap GEMM + fused BN partial sums ----------------
__global__ __launch_bounds__(256) void k_gemm_mfma3(const float* __restrict__ a0, const float* __restrict__ a1,
                                                    const float* __restrict__ a2, const float* __restrict__ a3,
                                                    const ushort_t* __restrict__ Wh, const ushort_t* __restrict__ Wlo,
                                                    const float* __restrict__ b, float* __restrict__ y,
                                                    double* __restrict__ parts) {
  const int lane = threadIdx.x & 63;
  const int wave = threadIdx.x >> 6;          // 0..3
  const int ct0 = wave * 2;
  const int row = lane & 15;
  const int hi = lane >> 4;
  const int rb = blockIdx.x * 16;             // 625 blocks * 16 rows = 10000

  f32x4 acc[2];
#pragma unroll
  for (int c = 0; c < 2; ++c) {
    float bv = b[(ct0 + c) * 16 + row];
    acc[c][0] = bv; acc[c][1] = bv; acc[c][2] = bv; acc[c][3] = bv;
  }

  const float* aps[4] = {a0, a1, a2, a3};
#pragma unroll
  for (int t = 0; t < 4; ++t) {
    const float* at = aps[t];
#pragma unroll
    for (int kt = 0; kt < 4; ++kt) {
      const float* ap = at + (size_t)(rb + row) * 128 + kt * 32 + hi * 8;
      float4 fa = *(const float4*)(ap);
      float4 fb = *(const float4*)(ap + 4);
      float av[8] = {fa.x, fa.y, fa.z, fa.w, fb.x, fb.y, fb.z, fb.w};
      short8v ah, al;
#pragma unroll
      for (int j = 0; j < 8; ++j) {
        u32 h = f2bf(av[j]);
        float r = av[j] - bf2f(h);
        ah[j] = (short)h;
        al[j] = (short)f2bf(r);
      }
#pragma unroll
      for (int c = 0; c < 2; ++c) {
        size_t widx = ((((size_t)t * 4 + kt) * 8 + (ct0 + c)) * 64 + lane) * 8;
        short8v bh = *(const short8v*)(Wh + widx);
        short8v bl = *(const short8v*)(Wlo + widx);
        acc[c] = __builtin_amdgcn_mfma_f32_16x16x32_bf16(ah, bh, acc[c], 0, 0, 0);
        acc[c] = __builtin_amdgcn_mfma_f32_16x16x32_bf16(al, bh, acc[c], 0, 0, 0);
        acc[c] = __builtin_amdgcn_mfma_f32_16x16x32_bf16(ah, bl, acc[c], 0, 0, 0);
      }
    }
  }

#pragma unroll
  for (int c = 0; c < 2; ++c) {
#pragma unroll
    for (int r = 0; r < 4; ++r) {
      int grow = rb + hi * 4 + r;
      y[(size_t)grow * 128 + (ct0 + c) * 16 + row] = acc[c][r];
    }
  }

  // fused BN partials: per-channel sum/sumsq over this block's 16 rows.
  // lanes hi=0..3 (xor 16, 32) hold the 16 rows of channel (ct0+c)*16+row.
#pragma unroll
  for (int c = 0; c < 2; ++c) {
    double s = 0.0, ss = 0.0;
#pragma unroll
    for (int r = 0; r < 4; ++r) {
      double v = (double)acc[c][r];
      s += v;
      ss += v * v;
    }
    s += __shfl_xor(s, 16);
    ss += __shfl_xor(ss, 16);
    s += __shfl_xor(s, 32);
    ss += __shfl_xor(ss, 32);
    if (hi == 0) {
      int ch = (ct0 + c) * 16 + row;
      parts[(size_t)blockIdx.x * 256 + ch] = s;
      parts[(size_t)blockIdx.x * 256 + 128 + ch] = ss;
    }
  }
}

// ---------------- BN finalize: 1 block reduces parts[625][256] -> AB[256] ----------------
__global__ __launch_bounds__(256) void k_bnfin(const double* __restrict__ parts,
                                               const float* __restrict__ gamma, const float* __restrict__ beta,
                                               float* __restrict__ AB) {
  __shared__ double st[256];
  int t = threadIdx.x;
  double s = 0.0;
  for (int b = 0; b < 625; ++b) s += parts[(size_t)b * 256 + t];
  st[t] = s;
  __syncthreads();
  if (t < 128) {
    double mu = st[t] / (double)NA;
    double var = st[128 + t] / (double)NA - mu * mu;
    double rs = 1.0 / sqrt(var + 1e-5);
    AB[t] = (float)rs * gamma[t];
    AB[128 + t] = beta[t] - (float)(mu * rs) * gamma[t];
  }
}

// ---------------- BN apply + residual (+ optional fused readout) ----------------
__global__ __launch_bounds__(256) void k_bnapply(const float* __restrict__ y, const float* __restrict__ AB,
                                                 const float* __restrict__ Wread, const float* __restrict__ bread,
                                                 float* __restrict__ x, float* __restrict__ out, int doread) {
  __shared__ float sAB[256], sWr[256];
  int t = threadIdx.x;
  sAB[t] = AB[t];
  sWr[t] = Wread[t];
  __syncthreads();
  const int n4 = NA * 32;
  for (int i = blockIdx.x * 256 + t; i < n4; i += gridDim.x * 256) {
    float4 yv = ((const float4*)y)[i];
    int c = (i & 31) * 4;
    float v0 = yv.x * sAB[c + 0] + sAB[128 + c + 0];
    float v1 = yv.y * sAB[c + 1] + sAB[128 + c + 1];
    float v2 = yv.z * sAB[c + 2] + sAB[128 + c + 2];
    float v3 = yv.w * sAB[c + 3] + sAB[128 + c + 3];
    v0 = (v0 >= 0.f) ? v0 : 0.01f * v0;
    v1 = (v1 >= 0.f) ? v1 : 0.01f * v1;
    v2 = (v2 >= 0.f) ? v2 : 0.01f * v2;
    v3 = (v3 >= 0.f) ? v3 : 0.01f * v3;
    float4 xv = ((float4*)x)[i];
    xv.x += v0; xv.y += v1; xv.z += v2; xv.w += v3;
    ((float4*)x)[i] = xv;
    if (doread) {
      // 32 consecutive threads cover one row; tree-reduce x.Wread
      float a0 = xv.x * sWr[(c + 0) * 2] + xv.y * sWr[(c + 1) * 2] + xv.z * sWr[(c + 2) * 2] + xv.w * sWr[(c + 3) * 2];
      float a1 = xv.x * sWr[(c + 0) * 2 + 1] + xv.y * sWr[(c + 1) * 2 + 1] + xv.z * sWr[(c + 2) * 2 + 1] + xv.w * sWr[(c + 3) * 2 + 1];
#pragma unroll
      for (int o = 1; o < 32; o <<= 1) {
        a0 += __shfl_xor(a0, o);
        a1 += __shfl_xor(a1, o);
      }
      if ((i & 31) == 0) {
        int row = i >> 5;
        out[row * 2 + 0] = a0 + bread[0];
        out[row * 2 + 1] = a1 + bread[1];
      }
    }
  }
}

extern "C" void kernel_launch(void* const* d_in, const int* in_sizes, int n_in,
                              void* d_out, int out_size, void* d_ws, size_t ws_size,
                              hipStream_t stream) {
  (void)in_sizes; (void)n_in; (void)out_size; (void)ws_size;
  const float* own_obs = (const float*)d_in[0];
  const float2* apos = (const float2*)d_in[1];
  const float2* tpos = (const float2*)d_in[2];
  const float* W_self = (const float*)d_in[3];
  const float* b_self = (const float*)d_in[4];
  const float* agWl = (const float*)d_in[5];
  const float* agWr = (const float*)d_in[6];
  const float* agatt = (const float*)d_in[7];
  const float* agb = (const float*)d_in[8];
  const float* tgWl = (const float*)d_in[9];
  const float* tgWr = (const float*)d_in[10];
  const float* tgatt = (const float*)d_in[11];
  const float* tgb = (const float*)d_in[12];
  const float* gfW = (const float*)d_in[13];
  const float* gfb = (const float*)d_in[14];
  const float* bng = (const float*)d_in[15];
  const float* bnb = (const float*)d_in[16];
  const float* Wread = (const float*)d_in[17];
  const float* bread = (const float*)d_in[18];
  const int* ei = (const int*)d_in[19];
  const int* esrc = ei;
  const int* edst = ei + NE;

  char* w = (char*)d_ws;
  size_t off = 0;
  auto take = [&](size_t bytes) -> void* {
    void* p = w + off;
    off += (bytes + 255) & ~(size_t)255;
    return p;
  };
  int* a_idx = (int*)take((size_t)NA * KN * 4);
  int* t_idx = (int*)take((size_t)NA * KN * 4);
  int* a_cnt = (int*)take((size_t)NA * 4);
  int* t_cnt = (int*)take((size_t)NA * 4);
  float* x = (float*)take((size_t)NA * 128 * 4);
  float* y = (float*)take((size_t)NA * 128 * 4);
  float* sh1 = (float*)take((size_t)NA * 128 * 4);
  float* sh2 = (float*)take((size_t)NA * 128 * 4);
  float* sh3 = (float*)take((size_t)NA * 128 * 4);
  ushort_t* Wh = (ushort_t*)take((size_t)131072 * 2);
  ushort_t* Wlo = (ushort_t*)take((size_t)131072 * 2);
  double* parts = (double*)take((size_t)625 * 256 * 8);
  float* AB = (float*)take(256 * 4);
  int* deg = (int*)take((size_t)NA * 4);
  int* cur = (int*)take((size_t)NA * 4);
  int* rp = (int*)take((size_t)(NA + 1) * 4);
  int* col = (int*)take((size_t)NE * 4);
  int* chist = (int*)take((size_t)2 * NCELL * 4);
  int* crp = (int*)take((size_t)(2 * NCELL + 1) * 4);
  int* ccur = (int*)take((size_t)2 * NCELL * 4);
  float2* ps = (float2*)take((size_t)2 * NA * 8);
  int* pid = (int*)take((size_t)2 * NA * 4);

  // setup: zero+packw, hist+self, scans, scatters, nbr, GATs
  k_zero_packw<<<131072 / 256, 256, 0, stream>>>(deg, cur, chist, ccur, gfW, Wh, Wlo);
  k_hist_self<<<(NE + 2 * NA + 8 * NA + 255) / 256, 256, 0, stream>>>(edst, apos, tpos, deg, chist,
                                                                      own_obs, W_self, b_self, x);
  k_scan_all<<<2, 1024, 0, stream>>>(deg, rp, chist, crp);
  k_scatter_all<<<(NE + 2 * NA + 255) / 256, 256, 0, stream>>>(esrc, edst, rp, cur, col,
                                                               apos, tpos, crp, ccur, ps, pid);
  k_nbr2<<<(2 * NA + 255) / 256, 256, 0, stream>>>(apos, crp, ps, pid, a_idx, a_cnt, t_idx, t_cnt);
  k_gat2<<<2 * GATB, 64, 0, stream>>>(apos, tpos, a_idx, a_cnt, t_idx, t_cnt,
                                      agWl, agWr, agatt, agb, tgWl, tgWr, tgatt, tgb, x);

  // two graph-filter + BN + residual layers
  for (int l = 0; l < 2; ++l) {
    const ushort_t* Whl = Wh + (size_t)l * 65536;
    const ushort_t* Wll = Wlo + (size_t)l * 65536;
    const float* bl = gfb + (size_t)l * 128;
    const float* gl = bng + (size_t)l * 128;
    const float* bb = bnb + (size_t)l * 128;
    k_shift3<<<1256, 256, 0, stream>>>(x, sh1, rp, col);
    k_shift3<<<1256, 256, 0, stream>>>(sh1, sh2, rp, col);
    k_shift3<<<1256, 256, 0, stream>>>(sh2, sh3, rp, col);
    k_gemm_mfma3<<<NA / 16, 256, 0, stream>>>(x, sh1, sh2, sh3, Whl, Wll, bl, y, parts);
    k_bnfin<<<1, 256, 0, stream>>>(parts, gl, bb, AB);
    k_bnapply<<<256, 256, 0, stream>>>(y, AB, Wread, bread, x, (float*)d_out, l == 1 ? 1 : 0);
  }
}

// Round 9
// 251.224 us; speedup vs baseline: 1.2944x; 1.2944x over previous
//
#include <hip/hip_runtime.h>

typedef unsigned long long u64;
typedef unsigned int u32;
typedef unsigned short ushort_t;

#define NA 10000
#define NE 320000
#define KN 10
#define GRID 50
#define NCELL (GRID * GRID)      // 2500 cells of width 2.0 over [0,100)^2
#define GATB 157                 // ceil(NA/64)

typedef __attribute__((ext_vector_type(8))) short short8v;
typedef __attribute__((ext_vector_type(4))) float f32x4;

// ---------------- bf16 helpers (RNE) ----------------
__device__ __forceinline__ u32 f2bf(float f) {
  union { float f; u32 u; } v; v.f = f;
  return (v.u + 0x7fffu + ((v.u >> 16) & 1u)) >> 16;
}
__device__ __forceinline__ float bf2f(u32 b) {
  union { u32 u; float f; } v; v.u = b << 16;
  return v.f;
}

// ---------------- top-10 (d2,idx) maintenance ----------------
__device__ __forceinline__ void insert10(u64* top, u64 key) {
#pragma unroll
  for (int t = 9; t > 0; --t) {
    u64 prev = top[t - 1];
    u64 cur = top[t];
    top[t] = (key < prev) ? prev : ((key < cur) ? key : cur);
  }
  top[0] = (key < top[0]) ? key : top[0];
}

__device__ __forceinline__ int cell_of(float2 p) {
  int cx = (int)(p.x * 0.5f);            // exact: *0.5 is a pow2 multiply
  int cy = (int)(p.y * 0.5f);
  cx = min(max(cx, 0), GRID - 1);
  cy = min(max(cy, 0), GRID - 1);
  return cy * GRID + cx;
}

// ---------------- fused: zero counters + W repack (independent ranges) ----------------
__global__ __launch_bounds__(256) void k_zero_packw(int* __restrict__ deg, int* __restrict__ cur,
                                                    int* __restrict__ chist, int* __restrict__ ccur,
                                                    const float* __restrict__ gfW,
                                                    ushort_t* __restrict__ Wh, ushort_t* __restrict__ Wlo) {
  int i = blockIdx.x * 256 + threadIdx.x;
  if (i < NA) deg[i] = 0;
  else if (i < 2 * NA) cur[i - NA] = 0;
  else if (i < 2 * NA + 2 * NCELL) chist[i - 2 * NA] = 0;
  else if (i < 2 * NA + 4 * NCELL) ccur[i - 2 * NA - 2 * NCELL] = 0;
  if (i < 131072) {   // W repack: f32 [l][t][k][n] -> bf16 hi/lo B-frag layout
    int l = i >> 16;
    int rem = i & 65535;
    int t = rem >> 14;
    int k = (rem >> 7) & 127;
    int n = rem & 127;
    float v = gfW[(size_t)i];
    int kt = k >> 5;
    int hi = (k >> 3) & 3;
    int j = k & 7;
    int ct = n >> 4;
    int lane = hi * 16 + (n & 15);
    size_t dst = (((((size_t)(l * 4 + t) * 4 + kt) * 8 + ct) * 64 + lane) * 8 + j);
    u32 h = f2bf(v);
    float r = v - bf2f(h);
    Wh[dst] = (ushort_t)h;
    Wlo[dst] = (ushort_t)f2bf(r);
  }
}

// ---------------- fused: edge-degree hist + cell hist + self MLP ----------------
__global__ __launch_bounds__(256) void k_hist_self(const int* __restrict__ edst,
                                                   const float2* __restrict__ apos,
                                                   const float2* __restrict__ tpos,
                                                   int* __restrict__ deg, int* __restrict__ chist,
                                                   const float* __restrict__ own_obs,
                                                   const float* __restrict__ W_self, const float* __restrict__ b_self,
                                                   float* __restrict__ x) {
  __shared__ float sW[512], sb[64];
  int t = threadIdx.x;
  for (int i = t; i < 512; i += 256) sW[i] = W_self[i];
  if (t < 64) sb[t] = b_self[t];
  __syncthreads();
  int i = blockIdx.x * 256 + t;
  if (i < NE) {
    atomicAdd(&deg[edst[i]], 1);
  } else if (i < NE + 2 * NA) {
    int ii = i - NE;
    int graph = (ii >= NA) ? 1 : 0;
    int idx = ii - graph * NA;
    float2 p = graph ? tpos[idx] : apos[idx];
    atomicAdd(&chist[graph * NCELL + cell_of(p)], 1);
  } else if (i < NE + 2 * NA + 8 * NA) {
    int gid = i - NE - 2 * NA;
    int q = gid >> 3;
    int c8 = (gid & 7) * 8;
    const float4* op = (const float4*)(own_obs + (size_t)q * 8);
    float4 o0 = op[0], o1 = op[1];
    float obs[8] = {o0.x, o0.y, o0.z, o0.w, o1.x, o1.y, o1.z, o1.w};
    float out[8];
#pragma unroll
    for (int jj = 0; jj < 8; ++jj) {
      int c = c8 + jj;
      float s = sb[c];
#pragma unroll
      for (int k = 0; k < 8; ++k) s += obs[k] * sW[k * 64 + c];
      out[jj] = s;
    }
    float* xrow = x + (size_t)q * 128 + c8;
    *(float4*)(xrow) = make_float4(out[0], out[1], out[2], out[3]);
    *(float4*)(xrow + 4) = make_float4(out[4], out[5], out[6], out[7]);
  }
}

// ---------------- fused scans: block 0 = edge CSR, block 1 = cell CSR ----------------
__global__ __launch_bounds__(1024) void k_scan_all(const int* __restrict__ deg, int* __restrict__ rp,
                                                   const int* __restrict__ chist, int* __restrict__ crp) {
  __shared__ int part[1024];
  int t = threadIdx.x;
  const int* in;
  int* out;
  int per, tot;
  if (blockIdx.x == 0) { in = deg; out = rp; per = 10; tot = NA; }
  else { in = chist; out = crp; per = 5; tot = 2 * NCELL; }
  int beg = min(t * per, tot), end = min(beg + per, tot);
  int s = 0;
  for (int i = beg; i < end; ++i) s += in[i];
  part[t] = s;
  __syncthreads();
  for (int o = 1; o < 1024; o <<= 1) {
    int v = part[t];
    int u = (t >= o) ? part[t - o] : 0;
    __syncthreads();
    part[t] = v + u;
    __syncthreads();
  }
  int base = (t > 0) ? part[t - 1] : 0;
  for (int i = beg; i < end; ++i) { out[i] = base; base += in[i]; }
  if (t == 1023) out[tot] = part[1023];
}

// ---------------- fused scatters: edges into CSR, points into cells ----------------
__global__ __launch_bounds__(256) void k_scatter_all(const int* __restrict__ esrc, const int* __restrict__ edst,
                                                     const int* __restrict__ rp, int* __restrict__ cur,
                                                     int* __restrict__ col,
                                                     const float2* __restrict__ apos, const float2* __restrict__ tpos,
                                                     const int* __restrict__ crp, int* __restrict__ ccur,
                                                     float2* __restrict__ ps, int* __restrict__ pid) {
  int i = blockIdx.x * 256 + threadIdx.x;
  if (i < NE) {
    int d = edst[i];
    int p = atomicAdd(&cur[d], 1);
    col[rp[d] + p] = esrc[i];
  } else if (i < NE + 2 * NA) {
    int ii = i - NE;
    int graph = (ii >= NA) ? 1 : 0;
    int idx = ii - graph * NA;
    float2 p = graph ? tpos[idx] : apos[idx];
    int gc = graph * NCELL + cell_of(p);
    int o = crp[gc] + atomicAdd(&ccur[gc], 1);
    ps[o] = p;
    pid[o] = idx;
  }
}

// ---------------- binned neighbor search: exact top-10 within radius ----------------
__global__ __launch_bounds__(256) void k_nbr2(const float2* __restrict__ apos,
                                              const int* __restrict__ rp,
                                              const float2* __restrict__ ps, const int* __restrict__ pid,
                                              int* __restrict__ a_idx, int* __restrict__ a_cnt,
                                              int* __restrict__ t_idx, int* __restrict__ t_cnt) {
  int tid = blockIdx.x * 256 + threadIdx.x;
  if (tid >= 2 * NA) return;
  int graph = (tid >= NA) ? 1 : 0;
  int q = tid - graph * NA;
  float2 qp = apos[q];
  int cx = min(max((int)(qp.x * 0.5f), 0), GRID - 1);
  int cy = min(max((int)(qp.y * 0.5f), 0), GRID - 1);

  u64 top[10];
#pragma unroll
  for (int t = 0; t < 10; ++t) top[t] = ~0ull;

  int x0 = max(cx - 1, 0), x1 = min(cx + 1, GRID - 1);
  int y0 = max(cy - 1, 0), y1 = min(cy + 1, GRID - 1);
  for (int yy = y0; yy <= y1; ++yy) {
    int cb = graph * NCELL + yy * GRID + x0;
    int ce = graph * NCELL + yy * GRID + x1;
    int b = rp[cb], e = rp[ce + 1];   // contiguous cells -> contiguous points
    for (int j = b; j < e; ++j) {
      float2 kp = ps[j];
      float dx = qp.x - kp.x;
      float dy = qp.y - kp.y;
      float d2 = __fadd_rn(__fmul_rn(dx, dx), __fmul_rn(dy, dy));
      int g = pid[j];
      if (d2 <= 4.0f && !(graph == 0 && g == q)) {
        u64 key = ((u64)__float_as_uint(d2) << 32) | (u32)g;
        if (key < top[9]) insert10(top, key);
      }
    }
  }
  int cnt = 0;
#pragma unroll
  for (int t = 0; t < 10; ++t) cnt += (top[t] != ~0ull) ? 1 : 0;
  int* oi = graph ? t_idx : a_idx;
#pragma unroll
  for (int t = 0; t < 10; ++t) oi[(size_t)q * 10 + t] = (int)(u32)(top[t] & 0xffffffffu);
  if (graph) t_cnt[q] = cnt; else a_cnt[q] = cnt;
}

// ---------------- both GATs in one launch (blocks [0,157)=agent, [157,314)=target) ----------------
__global__ __launch_bounds__(64) void k_gat2(const float2* __restrict__ apos, const float2* __restrict__ tpos,
                                             const int* __restrict__ a_idx, const int* __restrict__ a_cnt,
                                             const int* __restrict__ t_idx, const int* __restrict__ t_cnt,
                                             const float* __restrict__ agWl, const float* __restrict__ agWr,
                                             const float* __restrict__ agatt, const float* __restrict__ agb,
                                             const float* __restrict__ tgWl, const float* __restrict__ tgWr,
                                             const float* __restrict__ tgatt, const float* __restrict__ tgb,
                                             float* __restrict__ x) {
  int graph = (blockIdx.x >= GATB) ? 1 : 0;
  int b0 = blockIdx.x - graph * GATB;
  const float2* srcpos = graph ? tpos : apos;
  const int* idx_all = graph ? t_idx : a_idx;
  const int* cnt_all = graph ? t_cnt : a_cnt;
  const float* Wl = graph ? tgWl : agWl;
  const float* Wr = graph ? tgWr : agWr;
  const float* att = graph ? tgatt : agatt;
  const float* bbp = graph ? tgb : agb;
  int outoff = graph ? 96 : 64;

  __shared__ float sWl[64], sWr[64], satt[32], sbb[32];
  int t = threadIdx.x;
  sWl[t] = Wl[t];
  sWr[t] = Wr[t];
  if (t < 32) { satt[t] = att[t]; sbb[t] = bbp[t]; }
  __syncthreads();
  int q = b0 * 64 + t;
  if (q >= NA) return;
  float2 qp = apos[q];
  float xr[32];
#pragma unroll
  for (int c = 0; c < 32; ++c) xr[c] = qp.x * sWr[c] + qp.y * sWr[32 + c];
  const int* il = idx_all + (size_t)q * 10;
  int cnt = cnt_all[q];
  int idx[10];
#pragma unroll
  for (int k = 0; k < 10; ++k) idx[k] = (k < cnt) ? il[k] : 0;
  float pv[10];
  float m = -1e30f;
#pragma unroll
  for (int k = 0; k < 10; ++k) {
    float2 p = srcpos[idx[k]];
    float s = 0.f;
#pragma unroll
    for (int c = 0; c < 32; ++c) {
      float xl = p.x * sWl[c] + p.y * sWl[32 + c];
      float g = xl + xr[c];
      g = (g >= 0.f) ? g : 0.2f * g;
      s += satt[c] * g;
    }
    pv[k] = s;
    m = (k < cnt) ? fmaxf(m, s) : m;
  }
  float sum = 0.f;
#pragma unroll
  for (int k = 0; k < 10; ++k) {
    float e = (k < cnt) ? expf(pv[k] - m) : 0.f;
    pv[k] = e;
    sum += e;
  }
  float inv = 1.f / (sum + 1e-16f);
  float out[32];
#pragma unroll
  for (int c = 0; c < 32; ++c) out[c] = sbb[c];
#pragma unroll
  for (int k = 0; k < 10; ++k) {
    float a = pv[k] * inv;
    float2 p = srcpos[idx[k]];   // re-gather: tables are L1/L2-hot
#pragma unroll
    for (int c = 0; c < 32; ++c) {
      float xl = p.x * sWl[c] + p.y * sWl[32 + c];
      out[c] += a * xl;
    }
  }
  float* xrow = x + (size_t)q * 128 + outoff;
#pragma unroll
  for (int c4 = 0; c4 < 8; ++c4)
    *(float4*)(xrow + c4 * 4) = make_float4(out[c4 * 4], out[c4 * 4 + 1], out[c4 * 4 + 2], out[c4 * 4 + 3]);
}

// ---------------- adjacency shift, XCD-partitioned channel halves ----------------
__global__ __launch_bounds__(256) void k_shift3(const float* __restrict__ xin, float* __restrict__ xout,
                                                const int* __restrict__ rp, const int* __restrict__ col) {
  int bid = blockIdx.x;                       // grid 1256
  int half = (bid & 7) >> 2;
  int slot = (bid >> 3) * 4 + (bid & 3);      // 0..627
  if (slot >= 625) return;
  int wid = threadIdx.x >> 6;
  int lane = threadIdx.x & 63;
  int q = lane >> 4;                          // quarter-wave owns one row
  int li = lane & 15;                         // 16 lanes x f32x4 = 64 channels
  int row = slot * 16 + wid * 4 + q;
  int beg = rp[row], end = rp[row + 1];
  const f32x4* x4 = (const f32x4*)xin;
  int base = half * 16 + li;
  f32x4 acc = {0.f, 0.f, 0.f, 0.f};
  int j = beg;
  for (; j + 1 < end; j += 2) {
    int s0 = col[j], s1 = col[j + 1];         // uniform in quarter -> broadcast
    f32x4 v0 = x4[(size_t)s0 * 32 + base];
    f32x4 v1 = x4[(size_t)s1 * 32 + base];
    acc += v0;
    acc += v1;
  }
  if (j < end) acc += x4[(size_t)col[j] * 32 + base];
  __builtin_nontemporal_store(acc, &((f32x4*)xout)[(size_t)row * 32 + base]);
}

// ---------------- MFMA 4-tap GEMM + fused BN partial sums (transposed parts) ----------------
__global__ __launch_bounds__(256) void k_gemm_mfma3(const float* __restrict__ a0, const float* __restrict__ a1,
                                                    const float* __restrict__ a2, const float* __restrict__ a3,
                                                    const ushort_t* __restrict__ Wh, const ushort_t* __restrict__ Wlo,
                                                    const float* __restrict__ b, float* __restrict__ y,
                                                    double* __restrict__ parts) {
  const int lane = threadIdx.x & 63;
  const int wave = threadIdx.x >> 6;          // 0..3
  const int ct0 = wave * 2;
  const int row = lane & 15;
  const int hi = lane >> 4;
  const int rb = blockIdx.x * 16;             // 625 blocks * 16 rows = 10000

  f32x4 acc[2];
#pragma unroll
  for (int c = 0; c < 2; ++c) {
    float bv = b[(ct0 + c) * 16 + row];
    acc[c][0] = bv; acc[c][1] = bv; acc[c][2] = bv; acc[c][3] = bv;
  }

  const float* aps[4] = {a0, a1, a2, a3};
#pragma unroll
  for (int t = 0; t < 4; ++t) {
    const float* at = aps[t];
#pragma unroll
    for (int kt = 0; kt < 4; ++kt) {
      const float* ap = at + (size_t)(rb + row) * 128 + kt * 32 + hi * 8;
      float4 fa = *(const float4*)(ap);
      float4 fb = *(const float4*)(ap + 4);
      float av[8] = {fa.x, fa.y, fa.z, fa.w, fb.x, fb.y, fb.z, fb.w};
      short8v ah, al;
#pragma unroll
      for (int j = 0; j < 8; ++j) {
        u32 h = f2bf(av[j]);
        float r = av[j] - bf2f(h);
        ah[j] = (short)h;
        al[j] = (short)f2bf(r);
      }
#pragma unroll
      for (int c = 0; c < 2; ++c) {
        size_t widx = ((((size_t)t * 4 + kt) * 8 + (ct0 + c)) * 64 + lane) * 8;
        short8v bh = *(const short8v*)(Wh + widx);
        short8v bl = *(const short8v*)(Wlo + widx);
        acc[c] = __builtin_amdgcn_mfma_f32_16x16x32_bf16(ah, bh, acc[c], 0, 0, 0);
        acc[c] = __builtin_amdgcn_mfma_f32_16x16x32_bf16(al, bh, acc[c], 0, 0, 0);
        acc[c] = __builtin_amdgcn_mfma_f32_16x16x32_bf16(ah, bl, acc[c], 0, 0, 0);
      }
    }
  }

#pragma unroll
  for (int c = 0; c < 2; ++c) {
#pragma unroll
    for (int r = 0; r < 4; ++r) {
      int grow = rb + hi * 4 + r;
      y[(size_t)grow * 128 + (ct0 + c) * 16 + row] = acc[c][r];
    }
  }

  // fused BN partials, TRANSPOSED layout: parts[ch][block] so bnfin reads contiguous.
#pragma unroll
  for (int c = 0; c < 2; ++c) {
    double s = 0.0, ss = 0.0;
#pragma unroll
    for (int r = 0; r < 4; ++r) {
      double v = (double)acc[c][r];
      s += v;
      ss += v * v;
    }
    s += __shfl_xor(s, 16);
    ss += __shfl_xor(ss, 16);
    s += __shfl_xor(s, 32);
    ss += __shfl_xor(ss, 32);
    if (hi == 0) {
      int ch = (ct0 + c) * 16 + row;
      parts[(size_t)ch * 625 + blockIdx.x] = s;
      parts[(size_t)(128 + ch) * 625 + blockIdx.x] = ss;
    }
  }
}

// ---------------- BN finalize: 128 blocks, one channel each (coalesced 5KB rows) ----------------
__global__ __launch_bounds__(256) void k_bnfin(const double* __restrict__ parts,
                                               const float* __restrict__ gamma, const float* __restrict__ beta,
                                               float* __restrict__ AB) {
  __shared__ double s0[256], s1[256];
  int ch = blockIdx.x;       // 0..127
  int t = threadIdx.x;
  const double* ps = parts + (size_t)ch * 625;
  const double* pq = parts + (size_t)(128 + ch) * 625;
  double a = 0.0, b = 0.0;
  for (int i = t; i < 625; i += 256) { a += ps[i]; b += pq[i]; }
  s0[t] = a;
  s1[t] = b;
  __syncthreads();
  for (int o = 128; o > 0; o >>= 1) {
    if (t < o) { s0[t] += s0[t + o]; s1[t] += s1[t + o]; }
    __syncthreads();
  }
  if (t == 0) {
    double mu = s0[0] / (double)NA;
    double var = s1[0] / (double)NA - mu * mu;
    double rs = 1.0 / sqrt(var + 1e-5);
    AB[ch] = (float)rs * gamma[ch];
    AB[128 + ch] = beta[ch] - (float)(mu * rs) * gamma[ch];
  }
}

// ---------------- BN apply + residual (+ optional fused readout) ----------------
__global__ __launch_bounds__(256) void k_bnapply(const float* __restrict__ y, const float* __restrict__ AB,
                                                 const float* __restrict__ Wread, const float* __restrict__ bread,
                                                 float* __restrict__ x, float* __restrict__ out, int doread) {
  __shared__ float sAB[256], sWr[256];
  int t = threadIdx.x;
  sAB[t] = AB[t];
  sWr[t] = Wread[t];
  __syncthreads();
  const int n4 = NA * 32;
  for (int i = blockIdx.x * 256 + t; i < n4; i += gridDim.x * 256) {
    float4 yv = ((const float4*)y)[i];
    int c = (i & 31) * 4;
    float v0 = yv.x * sAB[c + 0] + sAB[128 + c + 0];
    float v1 = yv.y * sAB[c + 1] + sAB[128 + c + 1];
    float v2 = yv.z * sAB[c + 2] + sAB[128 + c + 2];
    float v3 = yv.w * sAB[c + 3] + sAB[128 + c + 3];
    v0 = (v0 >= 0.f) ? v0 : 0.01f * v0;
    v1 = (v1 >= 0.f) ? v1 : 0.01f * v1;
    v2 = (v2 >= 0.f) ? v2 : 0.01f * v2;
    v3 = (v3 >= 0.f) ? v3 : 0.01f * v3;
    float4 xv = ((float4*)x)[i];
    xv.x += v0; xv.y += v1; xv.z += v2; xv.w += v3;
    ((float4*)x)[i] = xv;
    if (doread) {
      // 32 consecutive threads cover one row; tree-reduce x.Wread
      float a0 = xv.x * sWr[(c + 0) * 2] + xv.y * sWr[(c + 1) * 2] + xv.z * sWr[(c + 2) * 2] + xv.w * sWr[(c + 3) * 2];
      float a1 = xv.x * sWr[(c + 0) * 2 + 1] + xv.y * sWr[(c + 1) * 2 + 1] + xv.z * sWr[(c + 2) * 2 + 1] + xv.w * sWr[(c + 3) * 2 + 1];
#pragma unroll
      for (int o = 1; o < 32; o <<= 1) {
        a0 += __shfl_xor(a0, o);
        a1 += __shfl_xor(a1, o);
      }
      if ((i & 31) == 0) {
        int row = i >> 5;
        out[row * 2 + 0] = a0 + bread[0];
        out[row * 2 + 1] = a1 + bread[1];
      }
    }
  }
}

extern "C" void kernel_launch(void* const* d_in, const int* in_sizes, int n_in,
                              void* d_out, int out_size, void* d_ws, size_t ws_size,
                              hipStream_t stream) {
  (void)in_sizes; (void)n_in; (void)out_size; (void)ws_size;
  const float* own_obs = (const float*)d_in[0];
  const float2* apos = (const float2*)d_in[1];
  const float2* tpos = (const float2*)d_in[2];
  const float* W_self = (const float*)d_in[3];
  const float* b_self = (const float*)d_in[4];
  const float* agWl = (const float*)d_in[5];
  const float* agWr = (const float*)d_in[6];
  const float* agatt = (const float*)d_in[7];
  const float* agb = (const float*)d_in[8];
  const float* tgWl = (const float*)d_in[9];
  const float* tgWr = (const float*)d_in[10];
  const float* tgatt = (const float*)d_in[11];
  const float* tgb = (const float*)d_in[12];
  const float* gfW = (const float*)d_in[13];
  const float* gfb = (const float*)d_in[14];
  const float* bng = (const float*)d_in[15];
  const float* bnb = (const float*)d_in[16];
  const float* Wread = (const float*)d_in[17];
  const float* bread = (const float*)d_in[18];
  const int* ei = (const int*)d_in[19];
  const int* esrc = ei;
  const int* edst = ei + NE;

  char* w = (char*)d_ws;
  size_t off = 0;
  auto take = [&](size_t bytes) -> void* {
    void* p = w + off;
    off += (bytes + 255) & ~(size_t)255;
    return p;
  };
  int* a_idx = (int*)take((size_t)NA * KN * 4);
  int* t_idx = (int*)take((size_t)NA * KN * 4);
  int* a_cnt = (int*)take((size_t)NA * 4);
  int* t_cnt = (int*)take((size_t)NA * 4);
  float* x = (float*)take((size_t)NA * 128 * 4);
  float* y = (float*)take((size_t)NA * 128 * 4);
  float* sh1 = (float*)take((size_t)NA * 128 * 4);
  float* sh2 = (float*)take((size_t)NA * 128 * 4);
  float* sh3 = (float*)take((size_t)NA * 128 * 4);
  ushort_t* Wh = (ushort_t*)take((size_t)131072 * 2);
  ushort_t* Wlo = (ushort_t*)take((size_t)131072 * 2);
  double* parts = (double*)take((size_t)256 * 625 * 8);
  float* AB = (float*)take(256 * 4);
  int* deg = (int*)take((size_t)NA * 4);
  int* cur = (int*)take((size_t)NA * 4);
  int* rp = (int*)take((size_t)(NA + 1) * 4);
  int* col = (int*)take((size_t)NE * 4);
  int* chist = (int*)take((size_t)2 * NCELL * 4);
  int* crp = (int*)take((size_t)(2 * NCELL + 1) * 4);
  int* ccur = (int*)take((size_t)2 * NCELL * 4);
  float2* ps = (float2*)take((size_t)2 * NA * 8);
  int* pid = (int*)take((size_t)2 * NA * 4);

  // setup: zero+packw, hist+self, scans, scatters, nbr, GATs
  k_zero_packw<<<131072 / 256, 256, 0, stream>>>(deg, cur, chist, ccur, gfW, Wh, Wlo);
  k_hist_self<<<(NE + 2 * NA + 8 * NA + 255) / 256, 256, 0, stream>>>(edst, apos, tpos, deg, chist,
                                                                      own_obs, W_self, b_self, x);
  k_scan_all<<<2, 1024, 0, stream>>>(deg, rp, chist, crp);
  k_scatter_all<<<(NE + 2 * NA + 255) / 256, 256, 0, stream>>>(esrc, edst, rp, cur, col,
                                                               apos, tpos, crp, ccur, ps, pid);
  k_nbr2<<<(2 * NA + 255) / 256, 256, 0, stream>>>(apos, crp, ps, pid, a_idx, a_cnt, t_idx, t_cnt);
  k_gat2<<<2 * GATB, 64, 0, stream>>>(apos, tpos, a_idx, a_cnt, t_idx, t_cnt,
                                      agWl, agWr, agatt, agb, tgWl, tgWr, tgatt, tgb, x);

  // two graph-filter + BN + residual layers
  for (int l = 0; l < 2; ++l) {
    const ushort_t* Whl = Wh + (size_t)l * 65536;
    const ushort_t* Wll = Wlo + (size_t)l * 65536;
    const float* bl = gfb + (size_t)l * 128;
    const float* gl = bng + (size_t)l * 128;
    const float* bb = bnb + (size_t)l * 128;
    k_shift3<<<1256, 256, 0, stream>>>(x, sh1, rp, col);
    k_shift3<<<1256, 256, 0, stream>>>(sh1, sh2, rp, col);
    k_shift3<<<1256, 256, 0, stream>>>(sh2, sh3, rp, col);
    k_gemm_mfma3<<<NA / 16, 256, 0, stream>>>(x, sh1, sh2, sh3, Whl, Wll, bl, y, parts);
    k_bnfin<<<128, 256, 0, stream>>>(parts, gl, bb, AB);
    k_bnapply<<<256, 256, 0, stream>>>(y, AB, Wread, bread, x, (float*)d_out, l == 1 ? 1 : 0);
  }
}